// Round 5
// baseline (96.361 us; speedup 1.0000x reference)
//
#include <hip/hip_runtime.h>

#define EMB 512
#define NROWS 10000
#define NPAIRS 65536

typedef __bf16 bf16x8 __attribute__((ext_vector_type(8)));
typedef float  f32x4  __attribute__((ext_vector_type(4)));
typedef unsigned int u32x4 __attribute__((ext_vector_type(4)));

// Split fp32 pair into packed bf16-hi dword and bf16-lo dword (RNE both).
__device__ __forceinline__ void split2(float x0, float x1, unsigned* hw, unsigned* lw) {
    unsigned u0 = __float_as_uint(x0), u1 = __float_as_uint(x1);
    unsigned r0 = u0 + 0x7FFFu + ((u0 >> 16) & 1u);
    unsigned r1 = u1 + 0x7FFFu + ((u1 >> 16) & 1u);
    float h0 = __uint_as_float(r0 & 0xFFFF0000u);
    float h1 = __uint_as_float(r1 & 0xFFFF0000u);
    float l0 = x0 - h0, l1 = x1 - h1;                 // exact
    unsigned v0 = __float_as_uint(l0), v1 = __float_as_uint(l1);
    unsigned s0 = v0 + 0x7FFFu + ((v0 >> 16) & 1u);
    unsigned s1 = v1 + 0x7FFFu + ((v1 >> 16) & 1u);
    *hw = (r0 >> 16) | (r1 & 0xFFFF0000u);
    *lw = (s0 >> 16) | (s1 & 0xFFFF0000u);
}

// ---------------- Kernel 0: pre-fragment W1 and W2 into MFMA lane-order bf16 hi/lo ----------
// W1F[t][kt(16)][nt(8)][lane(64)][i(8)]: k = kt*32 + 8*(lane>>4) + i (within table t),
//                                        n = nt*16 + (lane&15)
// W2F[kt(4)][nt(4)][lane(64)][i(8)]:     k = kt*32 + 8*(lane>>4) + i, n = nt*16 + (lane&15)
// Grid: 544 blocks x 256 = 139264 threads = 131072 (W1) + 8192 (W2), one element each.
__global__ __launch_bounds__(256)
void k0_fragment(const float* __restrict__ W1, const float* __restrict__ W2,
                 unsigned short* __restrict__ W1Fhi, unsigned short* __restrict__ W1Flo,
                 unsigned short* __restrict__ W2Fhi, unsigned short* __restrict__ W2Flo)
{
    int e = blockIdx.x * 256 + threadIdx.x;
    float x;
    unsigned short *hp, *lp;
    if (e < 131072) {
        int i  = e & 7;
        int l  = (e >> 3) & 63;
        int nt = (e >> 9) & 7;
        int kt = (e >> 12) & 15;
        int t  = e >> 16;
        int k = kt * 32 + 8 * (l >> 4) + i;
        int n = nt * 16 + (l & 15);
        x = W1[(t * 512 + k) * 128 + n];
        hp = W1Fhi + e; lp = W1Flo + e;
    } else {
        int e2 = e - 131072;
        int i  = e2 & 7;
        int l  = (e2 >> 3) & 63;
        int nt = (e2 >> 9) & 3;
        int kt = e2 >> 11;
        int k = kt * 32 + 8 * (l >> 4) + i;
        int n = nt * 16 + (l & 15);
        x = W2[k * 64 + n];
        hp = W2Fhi + e2; lp = W2Flo + e2;
    }
    unsigned u = __float_as_uint(x);
    unsigned r = u + 0x7FFFu + ((u >> 16) & 1u);
    float hf = __uint_as_float(r & 0xFFFF0000u);
    float lf = x - hf;
    unsigned v = __float_as_uint(lf);
    unsigned s = v + 0x7FFFu + ((v >> 16) & 1u);
    *hp = (unsigned short)(r >> 16);
    *lp = (unsigned short)(s >> 16);
}

// ---------------- Kernel 1: D = drug @ W1[:512,:] + b1, T = tgt @ W1[512:,:] ----------------
// Split-bf16 MFMA, no LDS. 626 blocks x 4 waves. Block: 32 rows x 128 cols, K=512.
// Wave w: M-tile mt = w&1, N-half nh = w>>1 (4 N-tiles). A-frags loaded directly from
// global (lane&15 = row, lane>>4 = k-octet), split to bf16 hi/lo in registers.
#define K1_BLOCKS 313  // ceil(10000/32)

__global__ __launch_bounds__(256)
void k1_mfma(const float* __restrict__ drug, const float* __restrict__ tgt,
             const unsigned* __restrict__ W1Fhi, const unsigned* __restrict__ W1Flo,
             const float* __restrict__ b1,
             float* __restrict__ D, float* __restrict__ T)
{
    int bid = blockIdx.x, tid = threadIdx.x;
    bool isT = bid >= K1_BLOCKS;
    int tb = isT ? bid - K1_BLOCKS : bid;
    const float* emb = isT ? tgt : drug;
    float* out = isT ? T : D;
    int row0 = tb * 32;

    int wave = tid >> 6, lane = tid & 63;
    int g = lane >> 4, lm = lane & 15;
    int mt = wave & 1, nh = wave >> 1;

    const u32x4* BH = (const u32x4*)W1Fhi + (isT ? 16 * 8 * 64 : 0);
    const u32x4* BL = (const u32x4*)W1Flo + (isT ? 16 * 8 * 64 : 0);

    int arow = row0 + mt * 16 + lm;
    int arow_c = arow < NROWS ? arow : NROWS - 1;    // clamp OOB reads (stores skipped)
    const float* abase = emb + (size_t)arow_c * EMB + 8 * g;

    f32x4 acc[4];
    #pragma unroll
    for (int j = 0; j < 4; j++) { acc[j][0]=0.f; acc[j][1]=0.f; acc[j][2]=0.f; acc[j][3]=0.f; }

    #pragma unroll 4
    for (int kt = 0; kt < 16; kt++) {
        float4 a0 = *(const float4*)(abase + kt * 32);
        float4 a1 = *(const float4*)(abase + kt * 32 + 4);
        unsigned h0, h1, h2, h3, l0, l1, l2, l3;
        split2(a0.x, a0.y, &h0, &l0);
        split2(a0.z, a0.w, &h1, &l1);
        split2(a1.x, a1.y, &h2, &l2);
        split2(a1.z, a1.w, &h3, &l3);
        u32x4 ah, al;
        ah[0]=h0; ah[1]=h1; ah[2]=h2; ah[3]=h3;
        al[0]=l0; al[1]=l1; al[2]=l2; al[3]=l3;
        bf16x8 Ah = __builtin_bit_cast(bf16x8, ah);
        bf16x8 Al = __builtin_bit_cast(bf16x8, al);
        #pragma unroll
        for (int j = 0; j < 4; j++) {
            int nt = nh * 4 + j;
            u32x4 bh = BH[(kt * 8 + nt) * 64 + lane];
            u32x4 bl = BL[(kt * 8 + nt) * 64 + lane];
            bf16x8 Bh = __builtin_bit_cast(bf16x8, bh);
            bf16x8 Bl = __builtin_bit_cast(bf16x8, bl);
            acc[j] = __builtin_amdgcn_mfma_f32_16x16x32_bf16(Ah, Bh, acc[j], 0, 0, 0);
            acc[j] = __builtin_amdgcn_mfma_f32_16x16x32_bf16(Ah, Bl, acc[j], 0, 0, 0);
            acc[j] = __builtin_amdgcn_mfma_f32_16x16x32_bf16(Al, Bh, acc[j], 0, 0, 0);
        }
    }

    // store: C row = mt*16 + 4g + reg, col = nt*16 + lm (verified map)
    #pragma unroll
    for (int j = 0; j < 4; j++) {
        int col = (nh * 4 + j) * 16 + lm;
        float bias = isT ? 0.f : b1[col];
        #pragma unroll
        for (int reg = 0; reg < 4; reg++) {
            int r = row0 + mt * 16 + 4 * g + reg;
            if (r < NROWS) out[r * 128 + col] = acc[j][reg] + bias;
        }
    }
}

// ---------------- Kernel 2: pair loss via split-bf16 MFMA ----------------
// 1024 blocks x 4 waves. Wave: 32 pairs (one set) = 64 rows, output 64x64, K=128
// processed per 32-k tile. Wave-private LDS 8 KB: 64 rows x 8 chunks x 16 B
// (chunks 0..3 hi, 4..7 lo), swizzle chunk ^= row&7 -> b128 floor both sides.
__global__ __launch_bounds__(256, 3)
void k2_pairs(const float* __restrict__ D, const float* __restrict__ T,
              const int* __restrict__ pos, const int* __restrict__ neg,
              const unsigned* __restrict__ W2Fhi, const unsigned* __restrict__ W2Flo,
              const float* __restrict__ b2, const float* __restrict__ W3,
              double* __restrict__ partials)
{
    __shared__ u32x4 Ash[4][512];   // 32 KB: per-wave 8 KB

    int tid = threadIdx.x;
    int wave = tid >> 6, lane = tid & 63;
    int g = lane >> 4, lm = lane & 15;
    int gw = blockIdx.x * 4 + wave;              // 0..4095
    const int* pairs = (gw < 2048) ? pos : neg;  // blocks 0..511 pos, 512..1023 neg
    int p0 = (gw & 2047) * 32;

    // phase-1 role: lane = row r: pair p0 + (r>>1), side r&1
    int p = p0 + (lane >> 1), side = lane & 1;
    int i0 = pairs[p * 3];
    int it = pairs[p * 3 + 1 + side];

    const float4* D4 = (const float4*)D;
    const float4* T4 = (const float4*)T;
    const u32x4* BH4 = (const u32x4*)W2Fhi;
    const u32x4* BL4 = (const u32x4*)W2Flo;
    u32x4* A4w = &Ash[wave][0];
    int wsw = lane & 7;                           // write swizzle key

    f32x4 acc[4][4];
    #pragma unroll
    for (int mt = 0; mt < 4; mt++)
        #pragma unroll
        for (int nt = 0; nt < 4; nt++) { acc[mt][nt][0]=0.f; acc[mt][nt][1]=0.f; acc[mt][nt][2]=0.f; acc[mt][nt][3]=0.f; }

    #pragma unroll 1
    for (int kt = 0; kt < 4; kt++) {
        // ---- phase 1: build h1 rows for k in [kt*32, kt*32+32) ----
        #pragma unroll
        for (int cc = 0; cc < 4; cc++) {
            float4 da = D4[i0 * 32 + kt * 8 + cc * 2];
            float4 db = D4[i0 * 32 + kt * 8 + cc * 2 + 1];
            float4 ta = T4[it * 32 + kt * 8 + cc * 2];
            float4 tb = T4[it * 32 + kt * 8 + cc * 2 + 1];
            float h0 = fmaxf(da.x + ta.x, 0.f), h1v = fmaxf(da.y + ta.y, 0.f);
            float h2 = fmaxf(da.z + ta.z, 0.f), h3 = fmaxf(da.w + ta.w, 0.f);
            float h4 = fmaxf(db.x + tb.x, 0.f), h5 = fmaxf(db.y + tb.y, 0.f);
            float h6 = fmaxf(db.z + tb.z, 0.f), h7 = fmaxf(db.w + tb.w, 0.f);
            unsigned hq0, hq1, hq2, hq3, lq0, lq1, lq2, lq3;
            split2(h0, h1v, &hq0, &lq0);
            split2(h2, h3,  &hq1, &lq1);
            split2(h4, h5,  &hq2, &lq2);
            split2(h6, h7,  &hq3, &lq3);
            u32x4 hq, lq;
            hq[0]=hq0; hq[1]=hq1; hq[2]=hq2; hq[3]=hq3;
            lq[0]=lq0; lq[1]=lq1; lq[2]=lq2; lq[3]=lq3;
            A4w[lane * 8 + (cc ^ wsw)]       = hq;
            A4w[lane * 8 + ((4 + cc) ^ wsw)] = lq;
        }
        asm volatile("s_waitcnt lgkmcnt(0)" ::: "memory");
        // ---- phase 2: MFMA for this K-tile ----
        u32x4 bh[4], bl[4];
        #pragma unroll
        for (int nt = 0; nt < 4; nt++) {
            bh[nt] = BH4[(kt * 4 + nt) * 64 + lane];
            bl[nt] = BL4[(kt * 4 + nt) * 64 + lane];
        }
        #pragma unroll
        for (int mt = 0; mt < 4; mt++) {
            int r = mt * 16 + lm, rs = r & 7;
            u32x4 ah = A4w[r * 8 + (g ^ rs)];
            u32x4 al = A4w[r * 8 + ((4 + g) ^ rs)];
            bf16x8 Ah = __builtin_bit_cast(bf16x8, ah);
            bf16x8 Al = __builtin_bit_cast(bf16x8, al);
            #pragma unroll
            for (int nt = 0; nt < 4; nt++) {
                bf16x8 Bh = __builtin_bit_cast(bf16x8, bh[nt]);
                bf16x8 Bl = __builtin_bit_cast(bf16x8, bl[nt]);
                acc[mt][nt] = __builtin_amdgcn_mfma_f32_16x16x32_bf16(Ah, Bh, acc[mt][nt], 0, 0, 0);
                acc[mt][nt] = __builtin_amdgcn_mfma_f32_16x16x32_bf16(Ah, Bl, acc[mt][nt], 0, 0, 0);
                acc[mt][nt] = __builtin_amdgcn_mfma_f32_16x16x32_bf16(Al, Bh, acc[mt][nt], 0, 0, 0);
            }
        }
        asm volatile("s_waitcnt lgkmcnt(0)" ::: "memory");  // reads done before next tile's writes
    }

    // ---- epilogue: layer 3 + pair diff ----
    // lane holds C rows mt*16 + 4g + reg, col nt*16 + lm.
    float b2v[4], w3v[4];
    #pragma unroll
    for (int nt = 0; nt < 4; nt++) { b2v[nt] = b2[nt * 16 + lm]; w3v[nt] = W3[nt * 16 + lm]; }

    float pr[4][4];
    #pragma unroll
    for (int mt = 0; mt < 4; mt++)
        #pragma unroll
        for (int reg = 0; reg < 4; reg++) {
            float s = 0.f;
            #pragma unroll
            for (int nt = 0; nt < 4; nt++) {
                float h2 = fmaxf(acc[mt][nt][reg] + b2v[nt], 0.f);
                s = fmaf(h2, w3v[nt], s);
            }
            pr[mt][reg] = s;
        }
    // reduce over the 16 lanes sharing g (cols)
    #pragma unroll
    for (int m = 1; m <= 8; m <<= 1)
        #pragma unroll
        for (int mt = 0; mt < 4; mt++)
            #pragma unroll
            for (int reg = 0; reg < 4; reg++)
                pr[mt][reg] += __shfl_xor(pr[mt][reg], m, 64);

    // rows in this lane: r = mt*16 + 4g + reg; pairs = (reg0,reg1),(reg2,reg3)
    double dsq = 0.0;
    #pragma unroll
    for (int mt = 0; mt < 4; mt++) {
        float d0 = pr[mt][0] - pr[mt][1];
        float d1 = pr[mt][2] - pr[mt][3];
        dsq += (double)d0 * (double)d0 + (double)d1 * (double)d1;
    }
    // sum the 4 g-groups
    dsq += __shfl_xor(dsq, 16, 64);
    dsq += __shfl_xor(dsq, 32, 64);

    __syncthreads();
    if (lane == 0) ((double*)&Ash[wave][0])[0] = dsq;
    __syncthreads();
    if (tid == 0) {
        double sum = 0.0;
        #pragma unroll
        for (int w = 0; w < 4; w++) sum += ((double*)&Ash[w][0])[0];
        partials[blockIdx.x] = sum;   // 0..511 pos, 512..1023 neg
    }
}

// ---------------- Kernel 3: final reduction ----------------
__global__ void k3_final(const double* __restrict__ partials, float* __restrict__ out)
{
    int lane = threadIdx.x;  // 64 threads
    double sp = 0.0, sn = 0.0;
    #pragma unroll
    for (int i = 0; i < 8; i++) {
        sp += partials[lane + 64 * i];
        sn += partials[512 + lane + 64 * i];
    }
    #pragma unroll
    for (int m = 1; m <= 32; m <<= 1) {
        sp += __shfl_xor(sp, m, 64);
        sn += __shfl_xor(sn, m, 64);
    }
    if (lane == 0) out[0] = (float)((sp - sn) / (double)NPAIRS);
}

extern "C" void kernel_launch(void* const* d_in, const int* in_sizes, int n_in,
                              void* d_out, int out_size, void* d_ws, size_t ws_size,
                              hipStream_t stream) {
    const int*   pos  = (const int*)d_in[0];
    const int*   neg  = (const int*)d_in[1];
    const float* drug = (const float*)d_in[2];
    const float* tgt  = (const float*)d_in[3];
    const float* W1   = (const float*)d_in[4];
    const float* b1   = (const float*)d_in[5];
    const float* W2   = (const float*)d_in[6];
    const float* b2   = (const float*)d_in[7];
    const float* W3   = (const float*)d_in[8];
    // d_in[9] = b3: cancels in a1 - a2, unused

    float* Dp = (float*)d_ws;                       // 10000*128 floats
    float* Tp = Dp + NROWS * 128;                   // 10000*128 floats
    char* base = (char*)(Tp + NROWS * 128);
    unsigned short* W2Fhi = (unsigned short*)base;            // 8192 ushort = 16 KB
    unsigned short* W2Flo = W2Fhi + 8192;                     // 16 KB
    unsigned short* W1Fhi = W2Flo + 8192;                     // 131072 ushort = 256 KB
    unsigned short* W1Flo = W1Fhi + 131072;                   // 256 KB
    double* partials = (double*)(W1Flo + 131072);             // 1024 doubles
    float* out = (float*)d_out;

    k0_fragment<<<544, 256, 0, stream>>>(W1, W2, W1Fhi, W1Flo, W2Fhi, W2Flo);
    k1_mfma<<<2 * K1_BLOCKS, 256, 0, stream>>>(drug, tgt, (const unsigned*)W1Fhi,
                                               (const unsigned*)W1Flo, b1, Dp, Tp);
    k2_pairs<<<1024, 256, 0, stream>>>(Dp, Tp, pos, neg, (const unsigned*)W2Fhi,
                                       (const unsigned*)W2Flo, b2, W3, partials);
    k3_final<<<1, 64, 0, stream>>>(partials, out);
}

// Round 6
// 71.691 us; speedup vs baseline: 1.3441x; 1.3441x over previous
//
#include <hip/hip_runtime.h>

#define EMB 512
#define NROWS 10000
#define NPAIRS 65536

typedef __bf16 bf16x8 __attribute__((ext_vector_type(8)));
typedef float  f32x4  __attribute__((ext_vector_type(4)));
typedef unsigned int u32x4 __attribute__((ext_vector_type(4)));

// Split fp32 pair into packed bf16-hi dword and bf16-lo dword (RNE both).
__device__ __forceinline__ void split2(float x0, float x1, unsigned* hw, unsigned* lw) {
    unsigned u0 = __float_as_uint(x0), u1 = __float_as_uint(x1);
    unsigned r0 = u0 + 0x7FFFu + ((u0 >> 16) & 1u);
    unsigned r1 = u1 + 0x7FFFu + ((u1 >> 16) & 1u);
    float h0 = __uint_as_float(r0 & 0xFFFF0000u);
    float h1 = __uint_as_float(r1 & 0xFFFF0000u);
    float l0 = x0 - h0, l1 = x1 - h1;                 // exact
    unsigned v0 = __float_as_uint(l0), v1 = __float_as_uint(l1);
    unsigned s0 = v0 + 0x7FFFu + ((v0 >> 16) & 1u);
    unsigned s1 = v1 + 0x7FFFu + ((v1 >> 16) & 1u);
    *hw = (r0 >> 16) | (r1 & 0xFFFF0000u);
    *lw = (s0 >> 16) | (s1 & 0xFFFF0000u);
}

// ---------------- Kernel 0: pre-fragment W1 and W2 into MFMA lane-order bf16 hi/lo ----------
__global__ __launch_bounds__(256)
void k0_fragment(const float* __restrict__ W1, const float* __restrict__ W2,
                 unsigned short* __restrict__ W1Fhi, unsigned short* __restrict__ W1Flo,
                 unsigned short* __restrict__ W2Fhi, unsigned short* __restrict__ W2Flo)
{
    int e = blockIdx.x * 256 + threadIdx.x;
    float x;
    unsigned short *hp, *lp;
    if (e < 131072) {
        int i  = e & 7;
        int l  = (e >> 3) & 63;
        int nt = (e >> 9) & 7;
        int kt = (e >> 12) & 15;
        int t  = e >> 16;
        int k = kt * 32 + 8 * (l >> 4) + i;
        int n = nt * 16 + (l & 15);
        x = W1[(t * 512 + k) * 128 + n];
        hp = W1Fhi + e; lp = W1Flo + e;
    } else {
        int e2 = e - 131072;
        int i  = e2 & 7;
        int l  = (e2 >> 3) & 63;
        int nt = (e2 >> 9) & 3;
        int kt = e2 >> 11;
        int k = kt * 32 + 8 * (l >> 4) + i;
        int n = nt * 16 + (l & 15);
        x = W2[k * 64 + n];
        hp = W2Fhi + e2; lp = W2Flo + e2;
    }
    unsigned u = __float_as_uint(x);
    unsigned r = u + 0x7FFFu + ((u >> 16) & 1u);
    float hf = __uint_as_float(r & 0xFFFF0000u);
    float lf = x - hf;
    unsigned v = __float_as_uint(lf);
    unsigned s = v + 0x7FFFu + ((v >> 16) & 1u);
    *hp = (unsigned short)(r >> 16);
    *lp = (unsigned short)(s >> 16);
}

// ---------------- Kernel 1: D = drug @ W1[:512,:] + b1, T = tgt @ W1[512:,:] ----------------
// Split-bf16 MFMA, no LDS (unchanged from R5 — passed with absmax 0).
#define K1_BLOCKS 313  // ceil(10000/32)

__global__ __launch_bounds__(256)
void k1_mfma(const float* __restrict__ drug, const float* __restrict__ tgt,
             const unsigned* __restrict__ W1Fhi, const unsigned* __restrict__ W1Flo,
             const float* __restrict__ b1,
             float* __restrict__ D, float* __restrict__ T)
{
    int bid = blockIdx.x, tid = threadIdx.x;
    bool isT = bid >= K1_BLOCKS;
    int tb = isT ? bid - K1_BLOCKS : bid;
    const float* emb = isT ? tgt : drug;
    float* out = isT ? T : D;
    int row0 = tb * 32;

    int wave = tid >> 6, lane = tid & 63;
    int g = lane >> 4, lm = lane & 15;
    int mt = wave & 1, nh = wave >> 1;

    const u32x4* BH = (const u32x4*)W1Fhi + (isT ? 16 * 8 * 64 : 0);
    const u32x4* BL = (const u32x4*)W1Flo + (isT ? 16 * 8 * 64 : 0);

    int arow = row0 + mt * 16 + lm;
    int arow_c = arow < NROWS ? arow : NROWS - 1;    // clamp OOB reads (stores skipped)
    const float* abase = emb + (size_t)arow_c * EMB + 8 * g;

    f32x4 acc[4];
    #pragma unroll
    for (int j = 0; j < 4; j++) { acc[j][0]=0.f; acc[j][1]=0.f; acc[j][2]=0.f; acc[j][3]=0.f; }

    #pragma unroll 4
    for (int kt = 0; kt < 16; kt++) {
        float4 a0 = *(const float4*)(abase + kt * 32);
        float4 a1 = *(const float4*)(abase + kt * 32 + 4);
        unsigned h0, h1, h2, h3, l0, l1, l2, l3;
        split2(a0.x, a0.y, &h0, &l0);
        split2(a0.z, a0.w, &h1, &l1);
        split2(a1.x, a1.y, &h2, &l2);
        split2(a1.z, a1.w, &h3, &l3);
        u32x4 ah, al;
        ah[0]=h0; ah[1]=h1; ah[2]=h2; ah[3]=h3;
        al[0]=l0; al[1]=l1; al[2]=l2; al[3]=l3;
        bf16x8 Ah = __builtin_bit_cast(bf16x8, ah);
        bf16x8 Al = __builtin_bit_cast(bf16x8, al);
        #pragma unroll
        for (int j = 0; j < 4; j++) {
            int nt = nh * 4 + j;
            u32x4 bh = BH[(kt * 8 + nt) * 64 + lane];
            u32x4 bl = BL[(kt * 8 + nt) * 64 + lane];
            bf16x8 Bh = __builtin_bit_cast(bf16x8, bh);
            bf16x8 Bl = __builtin_bit_cast(bf16x8, bl);
            acc[j] = __builtin_amdgcn_mfma_f32_16x16x32_bf16(Ah, Bh, acc[j], 0, 0, 0);
            acc[j] = __builtin_amdgcn_mfma_f32_16x16x32_bf16(Ah, Bl, acc[j], 0, 0, 0);
            acc[j] = __builtin_amdgcn_mfma_f32_16x16x32_bf16(Al, Bh, acc[j], 0, 0, 0);
        }
    }

    #pragma unroll
    for (int j = 0; j < 4; j++) {
        int col = (nh * 4 + j) * 16 + lm;
        float bias = isT ? 0.f : b1[col];
        #pragma unroll
        for (int reg = 0; reg < 4; reg++) {
            int r = row0 + mt * 16 + 4 * g + reg;
            if (r < NROWS) out[r * 128 + col] = acc[j][reg] + bias;
        }
    }
}

// ---------------- Kernel 2: pair loss via split-bf16 MFMA, DMA-staged gathers ----------------
// 1024 blocks x 4 waves. Wave: 32 pairs (one set) = 96 physical rows (32 d + 64 t),
// K per 32-k tile. Phase 1: 12x global_load_lds dwordx4 — lane=(rr=lane>>3 row-slot,
// cc=lane&7 chunk-slot): 8 rows x 128 B contiguous per instr, LDS linear, global source
// chunk pre-swizzled (cc ^ (pr&7)) so reads are conflict-free (rule 21: src-perm==read-perm).
// Phase 2: read d+t chunks, relu+split in regs, feed MFMA directly (h1 used exactly once).
__global__ __launch_bounds__(256)
void k2_pairs(const float* __restrict__ D, const float* __restrict__ T,
              const int* __restrict__ pos, const int* __restrict__ neg,
              const unsigned* __restrict__ W2Fhi, const unsigned* __restrict__ W2Flo,
              const float* __restrict__ b2, const float* __restrict__ W3,
              double* __restrict__ partials)
{
    __shared__ u32x4 Ash[4][768];   // 48 KB: per-wave 12 KB = 96 rows x 8 float4 (one 32-k slice)

    int tid = threadIdx.x;
    int wave = tid >> 6, lane = tid & 63;
    int g = lane >> 4, lm = lane & 15;
    int rr = lane >> 3, cc = lane & 7;
    int gw = blockIdx.x * 4 + wave;              // 0..4095
    const int* pairs = (gw < 2048) ? pos : neg;  // blocks 0..511 pos, 512..1023 neg
    int p0 = (gw & 2047) * 32;

    // Preload the 12 per-lane gather base pointers (row pr = it*8 + rr, chunk cc^(pr&7)).
    // pr<32: d-row of pair pr; pr>=32: t-row of output row r=pr-32 (pair r>>1, side r&1).
    const float* bp[12];
    #pragma unroll
    for (int it = 0; it < 12; it++) {
        int pr = it * 8 + rr;
        int idxv;
        const float* src;
        if (pr < 32) { idxv = pairs[(p0 + pr) * 3]; src = D; }
        else { int q = pr - 32; idxv = pairs[(p0 + (q >> 1)) * 3 + 1 + (q & 1)]; src = T; }
        bp[it] = src + (size_t)idxv * 128 + ((cc ^ (pr & 7)) << 2);
    }

    u32x4* A4w = &Ash[wave][0];
    const u32x4* BH4 = (const u32x4*)W2Fhi;
    const u32x4* BL4 = (const u32x4*)W2Flo;

    f32x4 acc[4][4];
    #pragma unroll
    for (int mt = 0; mt < 4; mt++)
        #pragma unroll
        for (int nt = 0; nt < 4; nt++) { acc[mt][nt][0]=0.f; acc[mt][nt][1]=0.f; acc[mt][nt][2]=0.f; acc[mt][nt][3]=0.f; }

    #pragma unroll 1
    for (int kt = 0; kt < 4; kt++) {
        // ---- B fragments first: their L2 latency overlaps the DMA ----
        u32x4 bh[4], bl[4];
        #pragma unroll
        for (int nt = 0; nt < 4; nt++) {
            bh[nt] = BH4[(kt * 4 + nt) * 64 + lane];
            bl[nt] = BL4[(kt * 4 + nt) * 64 + lane];
        }
        // ---- phase 1: DMA 96 rows x 128 B (this kt slice) into LDS ----
        #pragma unroll
        for (int it = 0; it < 12; it++) {
            __builtin_amdgcn_global_load_lds(
                (const __attribute__((address_space(1))) void*)(bp[it] + kt * 32),
                (__attribute__((address_space(3))) void*)((char*)A4w + it * 1024),
                16, 0, 0);
        }
        asm volatile("s_waitcnt vmcnt(0)" ::: "memory");
        // ---- phase 2: per M-tile: LDS read d+t, relu+split, MFMA ----
        #pragma unroll
        for (int mt = 0; mt < 4; mt++) {
            int r = mt * 16 + lm;           // output row this lane feeds as A-fragment
            int p = r >> 1;                 // d-row index (pairs share d across sides)
            int ds = p & 7, ts = r & 7;     // read swizzle keys (t-row pr=32+r, (32+r)&7 = r&7)
            const f32x4* drow = (const f32x4*)(A4w + p * 8);
            const f32x4* trow = (const f32x4*)(A4w + (32 + r) * 8);
            f32x4 d0 = drow[(2 * g) ^ ds];
            f32x4 d1 = drow[(2 * g + 1) ^ ds];
            f32x4 t0 = trow[(2 * g) ^ ts];
            f32x4 t1 = trow[(2 * g + 1) ^ ts];
            float h0 = fmaxf(d0[0] + t0[0], 0.f), h1v = fmaxf(d0[1] + t0[1], 0.f);
            float h2 = fmaxf(d0[2] + t0[2], 0.f), h3 = fmaxf(d0[3] + t0[3], 0.f);
            float h4 = fmaxf(d1[0] + t1[0], 0.f), h5 = fmaxf(d1[1] + t1[1], 0.f);
            float h6 = fmaxf(d1[2] + t1[2], 0.f), h7 = fmaxf(d1[3] + t1[3], 0.f);
            unsigned hq0, hq1, hq2, hq3, lq0, lq1, lq2, lq3;
            split2(h0, h1v, &hq0, &lq0);
            split2(h2, h3,  &hq1, &lq1);
            split2(h4, h5,  &hq2, &lq2);
            split2(h6, h7,  &hq3, &lq3);
            u32x4 ah, al;
            ah[0]=hq0; ah[1]=hq1; ah[2]=hq2; ah[3]=hq3;
            al[0]=lq0; al[1]=lq1; al[2]=lq2; al[3]=lq3;
            bf16x8 Ah = __builtin_bit_cast(bf16x8, ah);
            bf16x8 Al = __builtin_bit_cast(bf16x8, al);
            #pragma unroll
            for (int nt = 0; nt < 4; nt++) {
                bf16x8 Bh = __builtin_bit_cast(bf16x8, bh[nt]);
                bf16x8 Bl = __builtin_bit_cast(bf16x8, bl[nt]);
                acc[mt][nt] = __builtin_amdgcn_mfma_f32_16x16x32_bf16(Ah, Bh, acc[mt][nt], 0, 0, 0);
                acc[mt][nt] = __builtin_amdgcn_mfma_f32_16x16x32_bf16(Ah, Bl, acc[mt][nt], 0, 0, 0);
                acc[mt][nt] = __builtin_amdgcn_mfma_f32_16x16x32_bf16(Al, Bh, acc[mt][nt], 0, 0, 0);
            }
        }
        asm volatile("s_waitcnt lgkmcnt(0)" ::: "memory");  // LDS reads done before next DMA overwrite
    }

    // ---- epilogue: layer 3 + pair diff (verified mapping: row mt*16+4g+reg, col nt*16+lm) ----
    float b2v[4], w3v[4];
    #pragma unroll
    for (int nt = 0; nt < 4; nt++) { b2v[nt] = b2[nt * 16 + lm]; w3v[nt] = W3[nt * 16 + lm]; }

    float pr[4][4];
    #pragma unroll
    for (int mt = 0; mt < 4; mt++)
        #pragma unroll
        for (int reg = 0; reg < 4; reg++) {
            float s = 0.f;
            #pragma unroll
            for (int nt = 0; nt < 4; nt++) {
                float h2 = fmaxf(acc[mt][nt][reg] + b2v[nt], 0.f);
                s = fmaf(h2, w3v[nt], s);
            }
            pr[mt][reg] = s;
        }
    #pragma unroll
    for (int m = 1; m <= 8; m <<= 1)
        #pragma unroll
        for (int mt = 0; mt < 4; mt++)
            #pragma unroll
            for (int reg = 0; reg < 4; reg++)
                pr[mt][reg] += __shfl_xor(pr[mt][reg], m, 64);

    double dsq = 0.0;
    #pragma unroll
    for (int mt = 0; mt < 4; mt++) {
        float d0 = pr[mt][0] - pr[mt][1];
        float d1 = pr[mt][2] - pr[mt][3];
        dsq += (double)d0 * (double)d0 + (double)d1 * (double)d1;
    }
    dsq += __shfl_xor(dsq, 16, 64);
    dsq += __shfl_xor(dsq, 32, 64);

    __syncthreads();
    if (lane == 0) ((double*)&Ash[wave][0])[0] = dsq;
    __syncthreads();
    if (tid == 0) {
        double sum = 0.0;
        #pragma unroll
        for (int w = 0; w < 4; w++) sum += ((double*)&Ash[w][0])[0];
        partials[blockIdx.x] = sum;   // 0..511 pos, 512..1023 neg
    }
}

// ---------------- Kernel 3: final reduction ----------------
__global__ void k3_final(const double* __restrict__ partials, float* __restrict__ out)
{
    int lane = threadIdx.x;  // 64 threads
    double sp = 0.0, sn = 0.0;
    #pragma unroll
    for (int i = 0; i < 8; i++) {
        sp += partials[lane + 64 * i];
        sn += partials[512 + lane + 64 * i];
    }
    #pragma unroll
    for (int m = 1; m <= 32; m <<= 1) {
        sp += __shfl_xor(sp, m, 64);
        sn += __shfl_xor(sn, m, 64);
    }
    if (lane == 0) out[0] = (float)((sp - sn) / (double)NPAIRS);
}

extern "C" void kernel_launch(void* const* d_in, const int* in_sizes, int n_in,
                              void* d_out, int out_size, void* d_ws, size_t ws_size,
                              hipStream_t stream) {
    const int*   pos  = (const int*)d_in[0];
    const int*   neg  = (const int*)d_in[1];
    const float* drug = (const float*)d_in[2];
    const float* tgt  = (const float*)d_in[3];
    const float* W1   = (const float*)d_in[4];
    const float* b1   = (const float*)d_in[5];
    const float* W2   = (const float*)d_in[6];
    const float* b2   = (const float*)d_in[7];
    const float* W3   = (const float*)d_in[8];
    // d_in[9] = b3: cancels in a1 - a2, unused

    float* Dp = (float*)d_ws;                       // 10000*128 floats
    float* Tp = Dp + NROWS * 128;                   // 10000*128 floats
    char* base = (char*)(Tp + NROWS * 128);
    unsigned short* W2Fhi = (unsigned short*)base;            // 8192 ushort = 16 KB
    unsigned short* W2Flo = W2Fhi + 8192;                     // 16 KB
    unsigned short* W1Fhi = W2Flo + 8192;                     // 131072 ushort = 256 KB
    unsigned short* W1Flo = W1Fhi + 131072;                   // 256 KB
    double* partials = (double*)(W1Flo + 131072);             // 1024 doubles
    float* out = (float*)d_out;

    k0_fragment<<<544, 256, 0, stream>>>(W1, W2, W1Fhi, W1Flo, W2Fhi, W2Flo);
    k1_mfma<<<2 * K1_BLOCKS, 256, 0, stream>>>(drug, tgt, (const unsigned*)W1Fhi,
                                               (const unsigned*)W1Flo, b1, Dp, Tp);
    k2_pairs<<<1024, 256, 0, stream>>>(Dp, Tp, pos, neg, (const unsigned*)W2Fhi,
                                       (const unsigned*)W2Flo, b2, W3, partials);
    k3_final<<<1, 64, 0, stream>>>(partials, out);
}

// Round 7
// 68.832 us; speedup vs baseline: 1.3999x; 1.0415x over previous
//
#include <hip/hip_runtime.h>

#define EMB 512
#define NROWS 10000
#define NPAIRS 65536

typedef __bf16 bf16x8 __attribute__((ext_vector_type(8)));
typedef float  f32x4  __attribute__((ext_vector_type(4)));
typedef unsigned int u32x4 __attribute__((ext_vector_type(4)));

// Split fp32 pair into packed bf16-hi dword and bf16-lo dword (RNE both).
__device__ __forceinline__ void split2(float x0, float x1, unsigned* hw, unsigned* lw) {
    unsigned u0 = __float_as_uint(x0), u1 = __float_as_uint(x1);
    unsigned r0 = u0 + 0x7FFFu + ((u0 >> 16) & 1u);
    unsigned r1 = u1 + 0x7FFFu + ((u1 >> 16) & 1u);
    float h0 = __uint_as_float(r0 & 0xFFFF0000u);
    float h1 = __uint_as_float(r1 & 0xFFFF0000u);
    float l0 = x0 - h0, l1 = x1 - h1;                 // exact
    unsigned v0 = __float_as_uint(l0), v1 = __float_as_uint(l1);
    unsigned s0 = v0 + 0x7FFFu + ((v0 >> 16) & 1u);
    unsigned s1 = v1 + 0x7FFFu + ((v1 >> 16) & 1u);
    *hw = (r0 >> 16) | (r1 & 0xFFFF0000u);
    *lw = (s0 >> 16) | (s1 & 0xFFFF0000u);
}

// ---------------- Kernel 0: pre-fragment W1 and W2 into MFMA lane-order bf16 hi/lo ----------
__global__ __launch_bounds__(256)
void k0_fragment(const float* __restrict__ W1, const float* __restrict__ W2,
                 unsigned short* __restrict__ W1Fhi, unsigned short* __restrict__ W1Flo,
                 unsigned short* __restrict__ W2Fhi, unsigned short* __restrict__ W2Flo)
{
    int e = blockIdx.x * 256 + threadIdx.x;
    float x;
    unsigned short *hp, *lp;
    if (e < 131072) {
        int i  = e & 7;
        int l  = (e >> 3) & 63;
        int nt = (e >> 9) & 7;
        int kt = (e >> 12) & 15;
        int t  = e >> 16;
        int k = kt * 32 + 8 * (l >> 4) + i;
        int n = nt * 16 + (l & 15);
        x = W1[(t * 512 + k) * 128 + n];
        hp = W1Fhi + e; lp = W1Flo + e;
    } else {
        int e2 = e - 131072;
        int i  = e2 & 7;
        int l  = (e2 >> 3) & 63;
        int nt = (e2 >> 9) & 3;
        int kt = e2 >> 11;
        int k = kt * 32 + 8 * (l >> 4) + i;
        int n = nt * 16 + (l & 15);
        x = W2[k * 64 + n];
        hp = W2Fhi + e2; lp = W2Flo + e2;
    }
    unsigned u = __float_as_uint(x);
    unsigned r = u + 0x7FFFu + ((u >> 16) & 1u);
    float hf = __uint_as_float(r & 0xFFFF0000u);
    float lf = x - hf;
    unsigned v = __float_as_uint(lf);
    unsigned s = v + 0x7FFFu + ((v >> 16) & 1u);
    *hp = (unsigned short)(r >> 16);
    *lp = (unsigned short)(s >> 16);
}

// ---------------- Kernel 1: D = drug @ W1[:512,:] + b1, T = tgt @ W1[512:,:] ----------------
// Split-bf16 MFMA, no LDS. 1252 blocks (table x 313 row-tiles x 2 N-halves), 4 waves.
// Wave: 16 rows x 32 cols (mt = w&1, np = w>>1). Explicit 2-stage software pipeline:
// kt+1's 6 loads issue before kt's split+MFMA consume the current registers.
#define K1_RT 313  // 32-row tiles per table

__global__ __launch_bounds__(256)
void k1_mfma(const float* __restrict__ drug, const float* __restrict__ tgt,
             const unsigned* __restrict__ W1Fhi, const unsigned* __restrict__ W1Flo,
             const float* __restrict__ b1,
             float* __restrict__ D, float* __restrict__ T)
{
    int bid = blockIdx.x, tid = threadIdx.x;
    bool isT = bid >= 2 * K1_RT;
    int b2i = isT ? bid - 2 * K1_RT : bid;
    int rt = b2i >> 1, nh = b2i & 1;
    const float* emb = isT ? tgt : drug;
    float* out = isT ? T : D;
    int row0 = rt * 32;

    int wave = tid >> 6, lane = tid & 63;
    int g = lane >> 4, lm = lane & 15;
    int mt = wave & 1, np = wave >> 1;
    int ntb = nh * 4 + np * 2;          // this wave's 2 N-tiles: ntb, ntb+1

    const u32x4* BH = (const u32x4*)W1Fhi + (isT ? 8192 : 0);
    const u32x4* BL = (const u32x4*)W1Flo + (isT ? 8192 : 0);

    int arow = row0 + mt * 16 + lm;
    int arow_c = arow < NROWS ? arow : NROWS - 1;    // clamp OOB reads (stores skipped)
    const float* abase = emb + (size_t)arow_c * EMB + 8 * g;

    f32x4 acc[2];
    #pragma unroll
    for (int j = 0; j < 2; j++) { acc[j][0]=0.f; acc[j][1]=0.f; acc[j][2]=0.f; acc[j][3]=0.f; }

    // prologue: kt=0 loads
    float4 a0c = *(const float4*)(abase);
    float4 a1c = *(const float4*)(abase + 4);
    u32x4 bh0c = BH[(ntb) * 64 + lane];
    u32x4 bh1c = BH[(ntb + 1) * 64 + lane];
    u32x4 bl0c = BL[(ntb) * 64 + lane];
    u32x4 bl1c = BL[(ntb + 1) * 64 + lane];

    #pragma unroll
    for (int kt = 0; kt < 16; kt++) {
        float4 a0n, a1n;
        u32x4 bh0n, bh1n, bl0n, bl1n;
        if (kt < 15) {   // compile-time under full unroll
            a0n = *(const float4*)(abase + (kt + 1) * 32);
            a1n = *(const float4*)(abase + (kt + 1) * 32 + 4);
            bh0n = BH[((kt + 1) * 8 + ntb) * 64 + lane];
            bh1n = BH[((kt + 1) * 8 + ntb + 1) * 64 + lane];
            bl0n = BL[((kt + 1) * 8 + ntb) * 64 + lane];
            bl1n = BL[((kt + 1) * 8 + ntb + 1) * 64 + lane];
        }
        // split current A to bf16 hi/lo
        unsigned h0, h1, h2, h3, l0, l1, l2, l3;
        split2(a0c.x, a0c.y, &h0, &l0);
        split2(a0c.z, a0c.w, &h1, &l1);
        split2(a1c.x, a1c.y, &h2, &l2);
        split2(a1c.z, a1c.w, &h3, &l3);
        u32x4 ah, al;
        ah[0]=h0; ah[1]=h1; ah[2]=h2; ah[3]=h3;
        al[0]=l0; al[1]=l1; al[2]=l2; al[3]=l3;
        bf16x8 Ah = __builtin_bit_cast(bf16x8, ah);
        bf16x8 Al = __builtin_bit_cast(bf16x8, al);
        bf16x8 Bh0 = __builtin_bit_cast(bf16x8, bh0c);
        bf16x8 Bh1 = __builtin_bit_cast(bf16x8, bh1c);
        bf16x8 Bl0 = __builtin_bit_cast(bf16x8, bl0c);
        bf16x8 Bl1 = __builtin_bit_cast(bf16x8, bl1c);
        acc[0] = __builtin_amdgcn_mfma_f32_16x16x32_bf16(Ah, Bh0, acc[0], 0, 0, 0);
        acc[1] = __builtin_amdgcn_mfma_f32_16x16x32_bf16(Ah, Bh1, acc[1], 0, 0, 0);
        acc[0] = __builtin_amdgcn_mfma_f32_16x16x32_bf16(Ah, Bl0, acc[0], 0, 0, 0);
        acc[1] = __builtin_amdgcn_mfma_f32_16x16x32_bf16(Ah, Bl1, acc[1], 0, 0, 0);
        acc[0] = __builtin_amdgcn_mfma_f32_16x16x32_bf16(Al, Bh0, acc[0], 0, 0, 0);
        acc[1] = __builtin_amdgcn_mfma_f32_16x16x32_bf16(Al, Bh1, acc[1], 0, 0, 0);
        // rotate pipeline registers
        a0c = a0n; a1c = a1n;
        bh0c = bh0n; bh1c = bh1n; bl0c = bl0n; bl1c = bl1n;
    }

    // store: C row = mt*16 + 4g + reg, col = nt*16 + lm (verified map)
    #pragma unroll
    for (int j = 0; j < 2; j++) {
        int col = (ntb + j) * 16 + lm;
        float bias = isT ? 0.f : b1[col];
        #pragma unroll
        for (int reg = 0; reg < 4; reg++) {
            int r = row0 + mt * 16 + 4 * g + reg;
            if (r < NROWS) out[r * 128 + col] = acc[j][reg] + bias;
        }
    }
}

// ---------------- Kernel 2: pair loss via split-bf16 MFMA, DMA-staged gathers ----------------
// (unchanged from R6 — 96 rows per wave via global_load_lds, src-pre-swizzled chunks)
__global__ __launch_bounds__(256)
void k2_pairs(const float* __restrict__ D, const float* __restrict__ T,
              const int* __restrict__ pos, const int* __restrict__ neg,
              const unsigned* __restrict__ W2Fhi, const unsigned* __restrict__ W2Flo,
              const float* __restrict__ b2, const float* __restrict__ W3,
              double* __restrict__ partials)
{
    __shared__ u32x4 Ash[4][768];   // 48 KB: per-wave 12 KB = 96 rows x 8 float4 (one 32-k slice)

    int tid = threadIdx.x;
    int wave = tid >> 6, lane = tid & 63;
    int g = lane >> 4, lm = lane & 15;
    int rr = lane >> 3, cc = lane & 7;
    int gw = blockIdx.x * 4 + wave;              // 0..4095
    const int* pairs = (gw < 2048) ? pos : neg;  // blocks 0..511 pos, 512..1023 neg
    int p0 = (gw & 2047) * 32;

    const float* bp[12];
    #pragma unroll
    for (int it = 0; it < 12; it++) {
        int pr = it * 8 + rr;
        int idxv;
        const float* src;
        if (pr < 32) { idxv = pairs[(p0 + pr) * 3]; src = D; }
        else { int q = pr - 32; idxv = pairs[(p0 + (q >> 1)) * 3 + 1 + (q & 1)]; src = T; }
        bp[it] = src + (size_t)idxv * 128 + ((cc ^ (pr & 7)) << 2);
    }

    u32x4* A4w = &Ash[wave][0];
    const u32x4* BH4 = (const u32x4*)W2Fhi;
    const u32x4* BL4 = (const u32x4*)W2Flo;

    f32x4 acc[4][4];
    #pragma unroll
    for (int mt = 0; mt < 4; mt++)
        #pragma unroll
        for (int nt = 0; nt < 4; nt++) { acc[mt][nt][0]=0.f; acc[mt][nt][1]=0.f; acc[mt][nt][2]=0.f; acc[mt][nt][3]=0.f; }

    #pragma unroll 1
    for (int kt = 0; kt < 4; kt++) {
        u32x4 bh[4], bl[4];
        #pragma unroll
        for (int nt = 0; nt < 4; nt++) {
            bh[nt] = BH4[(kt * 4 + nt) * 64 + lane];
            bl[nt] = BL4[(kt * 4 + nt) * 64 + lane];
        }
        #pragma unroll
        for (int it = 0; it < 12; it++) {
            __builtin_amdgcn_global_load_lds(
                (const __attribute__((address_space(1))) void*)(bp[it] + kt * 32),
                (__attribute__((address_space(3))) void*)((char*)A4w + it * 1024),
                16, 0, 0);
        }
        asm volatile("s_waitcnt vmcnt(0)" ::: "memory");
        #pragma unroll
        for (int mt = 0; mt < 4; mt++) {
            int r = mt * 16 + lm;
            int p = r >> 1;
            int ds = p & 7, ts = r & 7;
            const f32x4* drow = (const f32x4*)(A4w + p * 8);
            const f32x4* trow = (const f32x4*)(A4w + (32 + r) * 8);
            f32x4 d0 = drow[(2 * g) ^ ds];
            f32x4 d1 = drow[(2 * g + 1) ^ ds];
            f32x4 t0 = trow[(2 * g) ^ ts];
            f32x4 t1 = trow[(2 * g + 1) ^ ts];
            float h0 = fmaxf(d0[0] + t0[0], 0.f), h1v = fmaxf(d0[1] + t0[1], 0.f);
            float h2 = fmaxf(d0[2] + t0[2], 0.f), h3 = fmaxf(d0[3] + t0[3], 0.f);
            float h4 = fmaxf(d1[0] + t1[0], 0.f), h5 = fmaxf(d1[1] + t1[1], 0.f);
            float h6 = fmaxf(d1[2] + t1[2], 0.f), h7 = fmaxf(d1[3] + t1[3], 0.f);
            unsigned hq0, hq1, hq2, hq3, lq0, lq1, lq2, lq3;
            split2(h0, h1v, &hq0, &lq0);
            split2(h2, h3,  &hq1, &lq1);
            split2(h4, h5,  &hq2, &lq2);
            split2(h6, h7,  &hq3, &lq3);
            u32x4 ah, al;
            ah[0]=hq0; ah[1]=hq1; ah[2]=hq2; ah[3]=hq3;
            al[0]=lq0; al[1]=lq1; al[2]=lq2; al[3]=lq3;
            bf16x8 Ah = __builtin_bit_cast(bf16x8, ah);
            bf16x8 Al = __builtin_bit_cast(bf16x8, al);
            #pragma unroll
            for (int nt = 0; nt < 4; nt++) {
                bf16x8 Bh = __builtin_bit_cast(bf16x8, bh[nt]);
                bf16x8 Bl = __builtin_bit_cast(bf16x8, bl[nt]);
                acc[mt][nt] = __builtin_amdgcn_mfma_f32_16x16x32_bf16(Ah, Bh, acc[mt][nt], 0, 0, 0);
                acc[mt][nt] = __builtin_amdgcn_mfma_f32_16x16x32_bf16(Ah, Bl, acc[mt][nt], 0, 0, 0);
                acc[mt][nt] = __builtin_amdgcn_mfma_f32_16x16x32_bf16(Al, Bh, acc[mt][nt], 0, 0, 0);
            }
        }
        asm volatile("s_waitcnt lgkmcnt(0)" ::: "memory");
    }

    float b2v[4], w3v[4];
    #pragma unroll
    for (int nt = 0; nt < 4; nt++) { b2v[nt] = b2[nt * 16 + lm]; w3v[nt] = W3[nt * 16 + lm]; }

    float pr[4][4];
    #pragma unroll
    for (int mt = 0; mt < 4; mt++)
        #pragma unroll
        for (int reg = 0; reg < 4; reg++) {
            float s = 0.f;
            #pragma unroll
            for (int nt = 0; nt < 4; nt++) {
                float h2 = fmaxf(acc[mt][nt][reg] + b2v[nt], 0.f);
                s = fmaf(h2, w3v[nt], s);
            }
            pr[mt][reg] = s;
        }
    #pragma unroll
    for (int m = 1; m <= 8; m <<= 1)
        #pragma unroll
        for (int mt = 0; mt < 4; mt++)
            #pragma unroll
            for (int reg = 0; reg < 4; reg++)
                pr[mt][reg] += __shfl_xor(pr[mt][reg], m, 64);

    double dsq = 0.0;
    #pragma unroll
    for (int mt = 0; mt < 4; mt++) {
        float d0 = pr[mt][0] - pr[mt][1];
        float d1 = pr[mt][2] - pr[mt][3];
        dsq += (double)d0 * (double)d0 + (double)d1 * (double)d1;
    }
    dsq += __shfl_xor(dsq, 16, 64);
    dsq += __shfl_xor(dsq, 32, 64);

    __syncthreads();
    if (lane == 0) ((double*)&Ash[wave][0])[0] = dsq;
    __syncthreads();
    if (tid == 0) {
        double sum = 0.0;
        #pragma unroll
        for (int w = 0; w < 4; w++) sum += ((double*)&Ash[w][0])[0];
        partials[blockIdx.x] = sum;   // 0..511 pos, 512..1023 neg
    }
}

// ---------------- Kernel 3: final reduction ----------------
__global__ void k3_final(const double* __restrict__ partials, float* __restrict__ out)
{
    int lane = threadIdx.x;  // 64 threads
    double sp = 0.0, sn = 0.0;
    #pragma unroll
    for (int i = 0; i < 8; i++) {
        sp += partials[lane + 64 * i];
        sn += partials[512 + lane + 64 * i];
    }
    #pragma unroll
    for (int m = 1; m <= 32; m <<= 1) {
        sp += __shfl_xor(sp, m, 64);
        sn += __shfl_xor(sn, m, 64);
    }
    if (lane == 0) out[0] = (float)((sp - sn) / (double)NPAIRS);
}

extern "C" void kernel_launch(void* const* d_in, const int* in_sizes, int n_in,
                              void* d_out, int out_size, void* d_ws, size_t ws_size,
                              hipStream_t stream) {
    const int*   pos  = (const int*)d_in[0];
    const int*   neg  = (const int*)d_in[1];
    const float* drug = (const float*)d_in[2];
    const float* tgt  = (const float*)d_in[3];
    const float* W1   = (const float*)d_in[4];
    const float* b1   = (const float*)d_in[5];
    const float* W2   = (const float*)d_in[6];
    const float* b2   = (const float*)d_in[7];
    const float* W3   = (const float*)d_in[8];
    // d_in[9] = b3: cancels in a1 - a2, unused

    float* Dp = (float*)d_ws;                       // 10000*128 floats
    float* Tp = Dp + NROWS * 128;                   // 10000*128 floats
    char* base = (char*)(Tp + NROWS * 128);
    unsigned short* W2Fhi = (unsigned short*)base;            // 8192 ushort = 16 KB
    unsigned short* W2Flo = W2Fhi + 8192;                     // 16 KB
    unsigned short* W1Fhi = W2Flo + 8192;                     // 131072 ushort = 256 KB
    unsigned short* W1Flo = W1Fhi + 131072;                   // 256 KB
    double* partials = (double*)(W1Flo + 131072);             // 1024 doubles
    float* out = (float*)d_out;

    k0_fragment<<<544, 256, 0, stream>>>(W1, W2, W1Fhi, W1Flo, W2Fhi, W2Flo);
    k1_mfma<<<4 * K1_RT, 256, 0, stream>>>(drug, tgt, (const unsigned*)W1Fhi,
                                           (const unsigned*)W1Flo, b1, Dp, Tp);
    k2_pairs<<<1024, 256, 0, stream>>>(Dp, Tp, pos, neg, (const unsigned*)W2Fhi,
                                       (const unsigned*)W2Flo, b2, W3, partials);
    k3_final<<<1, 64, 0, stream>>>(partials, out);
}

// Round 8
// 64.179 us; speedup vs baseline: 1.5014x; 1.0725x over previous
//
#include <hip/hip_runtime.h>

#define EMB 512
#define NROWS 10000
#define NPAIRS 65536

typedef __bf16 bf16x8 __attribute__((ext_vector_type(8)));
typedef float  f32x4  __attribute__((ext_vector_type(4)));
typedef unsigned int u32x4 __attribute__((ext_vector_type(4)));

// Split fp32 pair into packed bf16-hi dword and bf16-lo dword (RNE both).
__device__ __forceinline__ void split2(float x0, float x1, unsigned* hw, unsigned* lw) {
    unsigned u0 = __float_as_uint(x0), u1 = __float_as_uint(x1);
    unsigned r0 = u0 + 0x7FFFu + ((u0 >> 16) & 1u);
    unsigned r1 = u1 + 0x7FFFu + ((u1 >> 16) & 1u);
    float h0 = __uint_as_float(r0 & 0xFFFF0000u);
    float h1 = __uint_as_float(r1 & 0xFFFF0000u);
    float l0 = x0 - h0, l1 = x1 - h1;                 // exact
    unsigned v0 = __float_as_uint(l0), v1 = __float_as_uint(l1);
    unsigned s0 = v0 + 0x7FFFu + ((v0 >> 16) & 1u);
    unsigned s1 = v1 + 0x7FFFu + ((v1 >> 16) & 1u);
    *hw = (r0 >> 16) | (r1 & 0xFFFF0000u);
    *lw = (s0 >> 16) | (s1 & 0xFFFF0000u);
}

// ---------------- Kernel 0: pre-fragment W1 and W2 into MFMA lane-order bf16 hi/lo ----------
__global__ __launch_bounds__(256)
void k0_fragment(const float* __restrict__ W1, const float* __restrict__ W2,
                 unsigned short* __restrict__ W1Fhi, unsigned short* __restrict__ W1Flo,
                 unsigned short* __restrict__ W2Fhi, unsigned short* __restrict__ W2Flo)
{
    int e = blockIdx.x * 256 + threadIdx.x;
    float x;
    unsigned short *hp, *lp;
    if (e < 131072) {
        int i  = e & 7;
        int l  = (e >> 3) & 63;
        int nt = (e >> 9) & 7;
        int kt = (e >> 12) & 15;
        int t  = e >> 16;
        int k = kt * 32 + 8 * (l >> 4) + i;
        int n = nt * 16 + (l & 15);
        x = W1[(t * 512 + k) * 128 + n];
        hp = W1Fhi + e; lp = W1Flo + e;
    } else {
        int e2 = e - 131072;
        int i  = e2 & 7;
        int l  = (e2 >> 3) & 63;
        int nt = (e2 >> 9) & 3;
        int kt = e2 >> 11;
        int k = kt * 32 + 8 * (l >> 4) + i;
        int n = nt * 16 + (l & 15);
        x = W2[k * 64 + n];
        hp = W2Fhi + e2; lp = W2Flo + e2;
    }
    unsigned u = __float_as_uint(x);
    unsigned r = u + 0x7FFFu + ((u >> 16) & 1u);
    float hf = __uint_as_float(r & 0xFFFF0000u);
    float lf = x - hf;
    unsigned v = __float_as_uint(lf);
    unsigned s = v + 0x7FFFu + ((v >> 16) & 1u);
    *hp = (unsigned short)(r >> 16);
    *lp = (unsigned short)(s >> 16);
}

// ---------------- Kernel 1: D = drug @ W1[:512,:] + b1, T = tgt @ W1[512:,:] ----------------
// 2-phase double-buffered LDS pipeline (T3/T4 template). 626 blocks x 4 waves.
// Block: 32 rows x 128 cols, K=512 in 8 steps of 64. LDS 2 x 8 KB A-tile.
// Stage: 2 global_load_lds dwordx4 per wave per step (wave w stages rows w*8..w*8+8),
// source chunk pre-swizzled ((c&7)^(row&7)) so b128 reads are conflict-free.
#define K1_RT 313

__global__ __launch_bounds__(256)
void k1_mfma(const float* __restrict__ drug, const float* __restrict__ tgt,
             const unsigned* __restrict__ W1Fhi, const unsigned* __restrict__ W1Flo,
             const float* __restrict__ b1,
             float* __restrict__ D, float* __restrict__ T)
{
    __shared__ float Abuf[2][32 * 64];   // 2 x 8 KB

    int bid = blockIdx.x, tid = threadIdx.x;
    bool isT = bid >= K1_RT;
    int rt = isT ? bid - K1_RT : bid;
    const float* emb = isT ? tgt : drug;
    float* out = isT ? T : D;
    int row0 = rt * 32;

    int wave = tid >> 6, lane = tid & 63;
    int g = lane >> 4, lm = lane & 15;
    int mt = wave & 1, nh = wave >> 1;

    // stage mapping: instr it covers rows wave*8+it*4 .. +4, lane = (rr=lane>>4, cc=lane&15)
    int rr = lane >> 4, cc = lane & 15;
    const float* sp[2];
    #pragma unroll
    for (int it = 0; it < 2; it++) {
        int srow = row0 + wave * 8 + it * 4 + rr;
        if (srow > NROWS - 1) srow = NROWS - 1;      // clamp OOB (stores skipped)
        int schunk = (cc & 8) | ((cc & 7) ^ (srow & 7));   // pre-swizzled source chunk
        sp[it] = emb + (size_t)srow * EMB + schunk * 4;
    }

    const u32x4* BH = (const u32x4*)W1Fhi + (isT ? 8192 : 0);
    const u32x4* BL = (const u32x4*)W1Flo + (isT ? 8192 : 0);

    int r = mt * 16 + lm, rs = r & 7;

    f32x4 acc[4];
    #pragma unroll
    for (int j = 0; j < 4; j++) { acc[j][0]=0.f; acc[j][1]=0.f; acc[j][2]=0.f; acc[j][3]=0.f; }

    // prologue: stage step 0 into buf 0
    #pragma unroll
    for (int it = 0; it < 2; it++)
        __builtin_amdgcn_global_load_lds(
            (const __attribute__((address_space(1))) void*)(sp[it]),
            (__attribute__((address_space(3))) void*)((char*)&Abuf[0][0] + wave * 2048 + it * 1024),
            16, 0, 0);

    #pragma unroll
    for (int step = 0; step < 8; step++) {
        int cur = step & 1;
        // B fragments for this step (issued BEFORE next stage so vmcnt(2) keeps stage flying)
        u32x4 bh[2][4], bl[2][4];
        #pragma unroll
        for (int s = 0; s < 2; s++)
            #pragma unroll
            for (int j = 0; j < 4; j++) {
                int kt32 = step * 2 + s, nt = nh * 4 + j;
                bh[s][j] = BH[(kt32 * 8 + nt) * 64 + lane];
                bl[s][j] = BL[(kt32 * 8 + nt) * 64 + lane];
            }
        if (step < 7) {
            #pragma unroll
            for (int it = 0; it < 2; it++)
                __builtin_amdgcn_global_load_lds(
                    (const __attribute__((address_space(1))) void*)(sp[it] + (step + 1) * 64),
                    (__attribute__((address_space(3))) void*)((char*)&Abuf[cur ^ 1][0] + wave * 2048 + it * 1024),
                    16, 0, 0);
            asm volatile("s_waitcnt vmcnt(2)" ::: "memory");  // drains stage(step)+B; stage(step+1) flies
        } else {
            asm volatile("s_waitcnt vmcnt(0)" ::: "memory");
        }
        __builtin_amdgcn_s_barrier();    // all waves' stage(step) complete
        const f32x4* A4 = (const f32x4*)&Abuf[cur][0];
        #pragma unroll
        for (int s = 0; s < 2; s++) {
            f32x4 a0 = A4[r * 16 + s * 8 + ((2 * g) ^ rs)];
            f32x4 a1 = A4[r * 16 + s * 8 + ((2 * g + 1) ^ rs)];
            unsigned h0, h1, h2, h3, l0, l1, l2, l3;
            split2(a0[0], a0[1], &h0, &l0);
            split2(a0[2], a0[3], &h1, &l1);
            split2(a1[0], a1[1], &h2, &l2);
            split2(a1[2], a1[3], &h3, &l3);
            u32x4 ah, al;
            ah[0]=h0; ah[1]=h1; ah[2]=h2; ah[3]=h3;
            al[0]=l0; al[1]=l1; al[2]=l2; al[3]=l3;
            bf16x8 Ah = __builtin_bit_cast(bf16x8, ah);
            bf16x8 Al = __builtin_bit_cast(bf16x8, al);
            #pragma unroll
            for (int j = 0; j < 4; j++) {
                bf16x8 Bh = __builtin_bit_cast(bf16x8, bh[s][j]);
                bf16x8 Bl = __builtin_bit_cast(bf16x8, bl[s][j]);
                acc[j] = __builtin_amdgcn_mfma_f32_16x16x32_bf16(Ah, Bh, acc[j], 0, 0, 0);
                acc[j] = __builtin_amdgcn_mfma_f32_16x16x32_bf16(Ah, Bl, acc[j], 0, 0, 0);
                acc[j] = __builtin_amdgcn_mfma_f32_16x16x32_bf16(Al, Bh, acc[j], 0, 0, 0);
            }
        }
        asm volatile("s_waitcnt lgkmcnt(0)" ::: "memory");  // my LDS reads retired
        __builtin_amdgcn_s_barrier();                        // before anyone stages over cur
    }

    // store: C row = mt*16 + 4g + reg, col = nt*16 + lm (verified map)
    #pragma unroll
    for (int j = 0; j < 4; j++) {
        int col = (nh * 4 + j) * 16 + lm;
        float bias = isT ? 0.f : b1[col];
        #pragma unroll
        for (int reg = 0; reg < 4; reg++) {
            int row = row0 + mt * 16 + 4 * g + reg;
            if (row < NROWS) out[row * 128 + col] = acc[j][reg] + bias;
        }
    }
}

// ---------------- Kernel 2: pair loss, block-cooperative 2-phase pipeline ----------------
// 4096 blocks x 4 waves, 32 pairs/block (blocks 0..2047 pos, 2048..4095 neg).
// Staging: 96 physical rows (32 d + 64 t) per 32-k step, 12 KB, double-buffered (2x12 KB).
// Each wave stages rows [wave*24, wave*24+24) = 3 global_load_lds dwordx4; all 4 waves
// consume the shared slice (wave = mt). Counted vmcnt(3) keeps next stage in flight.
__global__ __launch_bounds__(256, 4)
void k2_pairs(const float* __restrict__ D, const float* __restrict__ T,
              const int* __restrict__ pos, const int* __restrict__ neg,
              const unsigned* __restrict__ W2Fhi, const unsigned* __restrict__ W2Flo,
              const float* __restrict__ b2, const float* __restrict__ W3,
              double* __restrict__ partials)
{
    __shared__ float Sbuf[2][96 * 32];   // 2 x 12 KB
    __shared__ double red[4];

    int tid = threadIdx.x, bid = blockIdx.x;
    int wave = tid >> 6, lane = tid & 63;
    int g = lane >> 4, lm = lane & 15;
    const int* pairs = (bid < 2048) ? pos : neg;
    int p0 = (bid & 2047) * 32;

    // stage source pointers: instr it covers rows pr = wave*24 + it*8 + rr
    int rr = lane >> 3, cc = lane & 7;
    const float* sp[3];
    #pragma unroll
    for (int it = 0; it < 3; it++) {
        int pr = wave * 24 + it * 8 + rr;
        int idxv;
        const float* src;
        if (pr < 32) { idxv = pairs[(p0 + pr) * 3]; src = D; }
        else { int q = pr - 32; idxv = pairs[(p0 + (q >> 1)) * 3 + 1 + (q & 1)]; src = T; }
        sp[it] = src + (size_t)idxv * 128 + ((cc ^ (pr & 7)) << 2);   // pre-swizzled chunk
    }

    const u32x4* BH4 = (const u32x4*)W2Fhi;
    const u32x4* BL4 = (const u32x4*)W2Flo;

    int mt = wave;                       // this wave's 16 output rows
    int r = mt * 16 + lm;
    int p = r >> 1;                      // d-row (pairs share d across sides)
    int ds = p & 7, ts = r & 7;          // read swizzle keys ((32+r)&7 == r&7)

    f32x4 acc[4];
    #pragma unroll
    for (int nt = 0; nt < 4; nt++) { acc[nt][0]=0.f; acc[nt][1]=0.f; acc[nt][2]=0.f; acc[nt][3]=0.f; }

    // prologue: stage step 0 into buf 0
    #pragma unroll
    for (int it = 0; it < 3; it++)
        __builtin_amdgcn_global_load_lds(
            (const __attribute__((address_space(1))) void*)(sp[it]),
            (__attribute__((address_space(3))) void*)((char*)&Sbuf[0][0] + wave * 3072 + it * 1024),
            16, 0, 0);

    #pragma unroll
    for (int step = 0; step < 4; step++) {
        int cur = step & 1;
        u32x4 bh[4], bl[4];
        #pragma unroll
        for (int nt = 0; nt < 4; nt++) {
            bh[nt] = BH4[(step * 4 + nt) * 64 + lane];
            bl[nt] = BL4[(step * 4 + nt) * 64 + lane];
        }
        if (step < 3) {
            #pragma unroll
            for (int it = 0; it < 3; it++)
                __builtin_amdgcn_global_load_lds(
                    (const __attribute__((address_space(1))) void*)(sp[it] + (step + 1) * 32),
                    (__attribute__((address_space(3))) void*)((char*)&Sbuf[cur ^ 1][0] + wave * 3072 + it * 1024),
                    16, 0, 0);
            asm volatile("s_waitcnt vmcnt(3)" ::: "memory");  // stage(step)+B drained; stage(step+1) flies
        } else {
            asm volatile("s_waitcnt vmcnt(0)" ::: "memory");
        }
        __builtin_amdgcn_s_barrier();    // slice(step) fully staged by all waves
        const f32x4* dS = (const f32x4*)&Sbuf[cur][0];
        f32x4 d0 = dS[p * 8 + ((2 * g) ^ ds)];
        f32x4 d1 = dS[p * 8 + ((2 * g + 1) ^ ds)];
        f32x4 t0 = dS[(32 + r) * 8 + ((2 * g) ^ ts)];
        f32x4 t1 = dS[(32 + r) * 8 + ((2 * g + 1) ^ ts)];
        float h0 = fmaxf(d0[0] + t0[0], 0.f), h1v = fmaxf(d0[1] + t0[1], 0.f);
        float h2 = fmaxf(d0[2] + t0[2], 0.f), h3 = fmaxf(d0[3] + t0[3], 0.f);
        float h4 = fmaxf(d1[0] + t1[0], 0.f), h5 = fmaxf(d1[1] + t1[1], 0.f);
        float h6 = fmaxf(d1[2] + t1[2], 0.f), h7 = fmaxf(d1[3] + t1[3], 0.f);
        unsigned hq0, hq1, hq2, hq3, lq0, lq1, lq2, lq3;
        split2(h0, h1v, &hq0, &lq0);
        split2(h2, h3,  &hq1, &lq1);
        split2(h4, h5,  &hq2, &lq2);
        split2(h6, h7,  &hq3, &lq3);
        u32x4 ah, al;
        ah[0]=hq0; ah[1]=hq1; ah[2]=hq2; ah[3]=hq3;
        al[0]=lq0; al[1]=lq1; al[2]=lq2; al[3]=lq3;
        bf16x8 Ah = __builtin_bit_cast(bf16x8, ah);
        bf16x8 Al = __builtin_bit_cast(bf16x8, al);
        #pragma unroll
        for (int nt = 0; nt < 4; nt++) {
            bf16x8 Bh = __builtin_bit_cast(bf16x8, bh[nt]);
            bf16x8 Bl = __builtin_bit_cast(bf16x8, bl[nt]);
            acc[nt] = __builtin_amdgcn_mfma_f32_16x16x32_bf16(Ah, Bh, acc[nt], 0, 0, 0);
            acc[nt] = __builtin_amdgcn_mfma_f32_16x16x32_bf16(Ah, Bl, acc[nt], 0, 0, 0);
            acc[nt] = __builtin_amdgcn_mfma_f32_16x16x32_bf16(Al, Bh, acc[nt], 0, 0, 0);
        }
        asm volatile("s_waitcnt lgkmcnt(0)" ::: "memory");
        __builtin_amdgcn_s_barrier();
    }

    // ---- epilogue: layer 3 + pair diff (C row = mt*16+4g+reg, col = nt*16+lm) ----
    float b2v[4], w3v[4];
    #pragma unroll
    for (int nt = 0; nt < 4; nt++) { b2v[nt] = b2[nt * 16 + lm]; w3v[nt] = W3[nt * 16 + lm]; }

    float pr[4];
    #pragma unroll
    for (int reg = 0; reg < 4; reg++) {
        float s = 0.f;
        #pragma unroll
        for (int nt = 0; nt < 4; nt++) {
            float h2 = fmaxf(acc[nt][reg] + b2v[nt], 0.f);
            s = fmaf(h2, w3v[nt], s);
        }
        pr[reg] = s;
    }
    #pragma unroll
    for (int m = 1; m <= 8; m <<= 1)
        #pragma unroll
        for (int reg = 0; reg < 4; reg++)
            pr[reg] += __shfl_xor(pr[reg], m, 64);

    float dd0 = pr[0] - pr[1];           // rows 4g+0/1 = one pair
    float dd1 = pr[2] - pr[3];           // rows 4g+2/3 = next pair
    double dsq = (double)dd0 * (double)dd0 + (double)dd1 * (double)dd1;
    dsq += __shfl_xor(dsq, 16, 64);
    dsq += __shfl_xor(dsq, 32, 64);

    if (lane == 0) red[wave] = dsq;
    __syncthreads();
    if (tid == 0) partials[bid] = red[0] + red[1] + red[2] + red[3];
}

// ---------------- Kernel 3: final reduction (4096 partials) ----------------
__global__ __launch_bounds__(256)
void k3_final(const double* __restrict__ partials, float* __restrict__ out)
{
    __shared__ double sred[2][4];
    int t = threadIdx.x;
    double sp = 0.0, sn = 0.0;
    #pragma unroll
    for (int i = 0; i < 8; i++) {
        sp += partials[t + 256 * i];
        sn += partials[2048 + t + 256 * i];
    }
    #pragma unroll
    for (int m = 1; m <= 32; m <<= 1) {
        sp += __shfl_xor(sp, m, 64);
        sn += __shfl_xor(sn, m, 64);
    }
    int wave = t >> 6, lane = t & 63;
    if (lane == 0) { sred[0][wave] = sp; sred[1][wave] = sn; }
    __syncthreads();
    if (t == 0) {
        double SP = sred[0][0] + sred[0][1] + sred[0][2] + sred[0][3];
        double SN = sred[1][0] + sred[1][1] + sred[1][2] + sred[1][3];
        out[0] = (float)((SP - SN) / (double)NPAIRS);
    }
}

extern "C" void kernel_launch(void* const* d_in, const int* in_sizes, int n_in,
                              void* d_out, int out_size, void* d_ws, size_t ws_size,
                              hipStream_t stream) {
    const int*   pos  = (const int*)d_in[0];
    const int*   neg  = (const int*)d_in[1];
    const float* drug = (const float*)d_in[2];
    const float* tgt  = (const float*)d_in[3];
    const float* W1   = (const float*)d_in[4];
    const float* b1   = (const float*)d_in[5];
    const float* W2   = (const float*)d_in[6];
    const float* b2   = (const float*)d_in[7];
    const float* W3   = (const float*)d_in[8];
    // d_in[9] = b3: cancels in a1 - a2, unused

    float* Dp = (float*)d_ws;                       // 10000*128 floats
    float* Tp = Dp + NROWS * 128;                   // 10000*128 floats
    char* base = (char*)(Tp + NROWS * 128);
    unsigned short* W2Fhi = (unsigned short*)base;            // 8192 ushort = 16 KB
    unsigned short* W2Flo = W2Fhi + 8192;                     // 16 KB
    unsigned short* W1Fhi = W2Flo + 8192;                     // 131072 ushort = 256 KB
    unsigned short* W1Flo = W1Fhi + 131072;                   // 256 KB
    double* partials = (double*)(W1Flo + 131072);             // 4096 doubles
    float* out = (float*)d_out;

    k0_fragment<<<544, 256, 0, stream>>>(W1, W2, W1Fhi, W1Flo, W2Fhi, W2Flo);
    k1_mfma<<<2 * K1_RT, 256, 0, stream>>>(drug, tgt, (const unsigned*)W1Fhi,
                                           (const unsigned*)W1Flo, b1, Dp, Tp);
    k2_pairs<<<4096, 256, 0, stream>>>(Dp, Tp, pos, neg, (const unsigned*)W2Fhi,
                                       (const unsigned*)W2Flo, b2, W3, partials);
    k3_final<<<1, 256, 0, stream>>>(partials, out);
}